// Round 10
// baseline (138.331 us; speedup 1.0000x reference)
//
#include <hip/hip_runtime.h>

// NTN: out[n,k] = relu( cos(x1 @ W1[k], x2 @ W2[k]) + [x1,x2]·V[k] + b[k] )
// N=32768, D=128, K=16.
// R13 = R3's math/fragments/epilogue with NO LDS and NO barriers.
// Pipe accounting of R3 (49.4us): LDS 20.5 + MFMA 16.6 + VALU ~15 ~= 52 ~= dur
// -> pipes serialized by the lockstep barrier schedule (R4-R12: occupancy,
// vmcnt counting, pipe-split, MFMA shape all null/worse — the schedule itself
// is the constraint). Fix: wsW is 1MB = L2-resident on every XCD; read W
// fragments DIRECT global->VGPR (same index algebra as the old LDS reads) in a
// 4-slot register ring prefetched 2 fragment-groups ahead (~300cy compute
// covers ~200cy L2 latency; R10's failure was 1-fg lookahead behind barriers).
// Waves free-run -> cross-wave MFMA/VMEM/VALU overlap. DS pipe ~2us (shfl only).
//  - fg = (kk, h, et): 8 frags (wa[4],wb[4]) = 32 VGPRs; ring slot = fg&3
//    (static after unroll: 8 fgs/kk, 8 == 0 mod 4).
//  - grid 512 = 256 rb x 2 kh (R3 mapping), 256thr/4 waves, rowbase verbatim.
//  - launch_bounds(256,1): R8/R12 lesson (arg2>=2 caps VGPR and spills).
//  - prep = R11 elementwise verbatim (same ws layouts; main is bit-identical
//    math -> absmax expected exactly 0.03125).

typedef __attribute__((ext_vector_type(8))) __bf16 bf16x8;
typedef __attribute__((ext_vector_type(8))) unsigned short us8;
typedef __attribute__((ext_vector_type(4))) float f32x4;

static __device__ __forceinline__ unsigned short f2bf(float f) {
  unsigned u = __float_as_uint(f);
  u += 0x7FFFu + ((u >> 16) & 1u);   // round-to-nearest-even
  return (unsigned short)(u >> 16);
}

static __device__ __forceinline__ bf16x8 as_bf(us8 u) {
  bf16x8 r;
  __builtin_memcpy(&r, &u, sizeof(r));
  return r;
}

// ---------------- prep (R11 elementwise, UNCHANGED layouts) ----------------
// wsW[t*8+j] = f2bf(W_side[k][d = s*32 + q*8 + j][e = (h*4+et')*16 + l15])
//   t: u=t&2047, cc=t>>11; lane=u&63, s=(u>>6)&3, et'=(u>>8)&3, side=(u>>10)&1;
//   h=cc&1, k=cc>>1; q=lane>>4, l15=lane&15.
// wsV[u*8+j] = f2bf(V[l15*256 + cs*32 + q*8 + j]), u: lane=u&63, cs=u>>6.
__global__ void ntn_prep(const float* __restrict__ W1, const float* __restrict__ W2,
                         const float* __restrict__ V,
                         unsigned short* __restrict__ wsW, unsigned short* __restrict__ wsV) {
  int e2 = blockIdx.x * 256 + threadIdx.x;
  if (e2 < 524288) {
    int j = e2 & 7, t = e2 >> 3;
    int u = t & 2047, cc = t >> 11;
    int lane = u & 63, s = (u >> 6) & 3, et2 = (u >> 8) & 3, side = (u >> 10) & 1;
    int h = cc & 1, k = cc >> 1;
    int q = lane >> 4, l15 = lane & 15;
    int et = h * 4 + et2;
    const float* W = side ? W2 : W1;
    wsW[e2] = f2bf(W[k * 16384 + (s * 32 + q * 8 + j) * 128 + (et * 16 + l15)]);
  } else if (e2 < 528384) {
    int v2 = e2 - 524288;
    int j = v2 & 7, u = v2 >> 3;
    int lane = u & 63, cs = u >> 6;
    int q = lane >> 4, l15 = lane & 15;
    wsV[v2] = f2bf(V[l15 * 256 + cs * 32 + q * 8 + j]);
  }
}

// ---------------- main (LDS-free, barrier-free) ----------------
__global__ __launch_bounds__(256, 1) void ntn_main(
    const float* __restrict__ x1, const float* __restrict__ x2,
    const float* __restrict__ b,
    const unsigned short* __restrict__ wsW, const unsigned short* __restrict__ wsV,
    float* __restrict__ out) {
  const int tid = threadIdx.x;
  const int lane = tid & 63, wave = tid >> 6;
  const int q = lane >> 4, l15 = lane & 15;
  const int kh = blockIdx.x & 1;          // k range [8kh, 8kh+8)
  const int rb = blockIdx.x >> 1;         // 128-row group
  const int rowbase = rb * 128 + wave * 32;

  const f32x4 zero4 = {0.f, 0.f, 0.f, 0.f};

  // ---- X fragments (B-operand), bf16, k-invariant, in registers (R3 verbatim)
  bf16x8 xb[2][2][4];
#pragma unroll
  for (int side = 0; side < 2; ++side) {
    const float* xp0 = side ? x2 : x1;
#pragma unroll
    for (int nt = 0; nt < 2; ++nt) {
#pragma unroll
      for (int s = 0; s < 4; ++s) {
        const float* p = xp0 + (size_t)(rowbase + nt * 16 + l15) * 128 + s * 32 + q * 8;
        float4 v0 = *(const float4*)p;
        float4 v1 = *(const float4*)(p + 4);
        us8 uu;
        uu[0] = f2bf(v0.x); uu[1] = f2bf(v0.y); uu[2] = f2bf(v0.z); uu[3] = f2bf(v0.w);
        uu[4] = f2bf(v1.x); uu[5] = f2bf(v1.y); uu[6] = f2bf(v1.z); uu[7] = f2bf(v1.w);
        xb[side][nt][s] = as_bf(uu);
      }
    }
  }

  // ---- part2 + b via MFMA (A = V frags; B = X frags), in registers (R3 verbatim)
  f32x4 accP[2];
  {
    bf16x8 vf[8];
#pragma unroll
    for (int cs = 0; cs < 8; ++cs)
      vf[cs] = as_bf(*(const us8*)(wsV + (size_t)(cs * 64 + lane) * 8));
    float4 bv = *(const float4*)(b + q * 4);
#pragma unroll
    for (int nt = 0; nt < 2; ++nt) {
      f32x4 a = zero4;
#pragma unroll
      for (int cs = 0; cs < 8; ++cs)
        a = __builtin_amdgcn_mfma_f32_16x16x32_bf16(vf[cs], xb[cs >> 2][nt][cs & 3], a, 0, 0, 0);
      a.x += bv.x; a.y += bv.y; a.z += bv.z; a.w += bv.w;
      accP[nt] = a;   // lane quad q holds part2+b for k = q*4 + reg
    }
  }

  // ---- W fragment ring: 4 slots x (wa[4], wb[4]); slot = fg & 3 ----
  bf16x8 wra[4][4], wrb[4][4];
  const us8* wsu = (const us8*)wsW;   // 16B units; unit index = cc*2048 + side*1024 + et*256 + s*64 + lane

  // load fragment-group (cc, et) into a slot: 8x global_load_dwordx4 (L2-hot)
  auto loadfg = [&](int slot, int cc, int et) {
    const us8* base = wsu + (size_t)cc * 2048 + et * 256 + lane;
#pragma unroll
    for (int s = 0; s < 4; ++s) wra[slot][s] = as_bf(base[s * 64]);
#pragma unroll
    for (int s = 0; s < 4; ++s) wrb[slot][s] = as_bf(base[1024 + s * 64]);
  };

  float nm[2] = {0.f, 0.f}, q1[2] = {0.f, 0.f}, q2[2] = {0.f, 0.f};

  // compute one fg from a ring slot (16 MFMA + folds; R3's per-et body)
  auto compute = [&](int slot) {
#pragma unroll
    for (int nt = 0; nt < 2; ++nt) {
      f32x4 a1 = zero4, a2 = zero4;
#pragma unroll
      for (int s = 0; s < 4; ++s)
        a1 = __builtin_amdgcn_mfma_f32_16x16x32_bf16(wra[slot][s], xb[0][nt][s], a1, 0, 0, 0);
#pragma unroll
      for (int s = 0; s < 4; ++s)
        a2 = __builtin_amdgcn_mfma_f32_16x16x32_bf16(wrb[slot][s], xb[1][nt][s], a2, 0, 0, 0);
      nm[nt] += a1.x * a2.x + a1.y * a2.y + a1.z * a2.z + a1.w * a2.w;
      q1[nt] += a1.x * a1.x + a1.y * a1.y + a1.z * a1.z + a1.w * a1.w;
      q2[nt] += a2.x * a2.x + a2.y * a2.y + a2.z * a2.z + a2.w * a2.w;
    }
  };

  // prologue: fg0, fg1 in flight
  loadfg(0, kh * 16 + 0, 0);
  loadfg(1, kh * 16 + 0, 1);

#pragma unroll 1
  for (int kk = 0; kk < 8; ++kk) {
#pragma unroll
    for (int i = 0; i < 8; ++i) {          // fg = kk*8 + i; i = h*4 + et
      const int nf = kk * 8 + i + 2;       // prefetch distance 2
      if (nf < 64) {
        const int ni = nf & 7;
        const int cc = kh * 16 + (nf >> 3) * 2 + (ni >> 2);
        loadfg((i + 2) & 3, cc, ni & 3);   // 8 == 0 mod 4 -> slot static per kk body
      }
      compute(i & 3);
    }

    const int k = kh * 8 + kk;
    const int qo = k >> 2;                 // owning lane quad
    const int r  = k & 3;
#pragma unroll
    for (int nt = 0; nt < 2; ++nt) {
      float n = nm[nt], s1 = q1[nt], s2 = q2[nt];
      n  += __shfl_xor(n, 16);  n  += __shfl_xor(n, 32);
      s1 += __shfl_xor(s1, 16); s1 += __shfl_xor(s1, 32);
      s2 += __shfl_xor(s2, 16); s2 += __shfl_xor(s2, 32);
      float d1 = fmaxf(sqrtf(s1), 1e-8f);
      float d2 = fmaxf(sqrtf(s2), 1e-8f);
      float p1 = n / (d1 * d2);
      float pc = (r == 0) ? accP[nt].x : (r == 1) ? accP[nt].y
               : (r == 2) ? accP[nt].z : accP[nt].w;
      if (q == qo)
        out[(size_t)(rowbase + nt * 16 + l15) * 16 + k] = fmaxf(p1 + pc, 0.f);
      nm[nt] = 0.f; q1[nt] = 0.f; q2[nt] = 0.f;
    }
  }
}

extern "C" void kernel_launch(void* const* d_in, const int* in_sizes, int n_in,
                              void* d_out, int out_size, void* d_ws, size_t ws_size,
                              hipStream_t stream) {
  const float* x1 = (const float*)d_in[0];
  const float* x2 = (const float*)d_in[1];
  const float* W1 = (const float*)d_in[2];
  const float* W2 = (const float*)d_in[3];
  const float* V  = (const float*)d_in[4];
  const float* b  = (const float*)d_in[5];
  float* out = (float*)d_out;
  unsigned short* wsW = (unsigned short*)d_ws;
  unsigned short* wsV = wsW + (size_t)65536 * 8;   // 1MB offset

  ntn_prep<<<2064, 256, 0, stream>>>(W1, W2, V, wsW, wsV);
  ntn_main<<<512, 256, 0, stream>>>(x1, x2, b, wsW, wsV, out);
}

// Round 11
// 134.828 us; speedup vs baseline: 1.0260x; 1.0260x over previous
//
#include <hip/hip_runtime.h>

// NTN: out[n,k] = relu( cos(x1 @ W1[k], x2 @ W2[k]) + [x1,x2]·V[k] + b[k] )
// N=32768, D=128, K=16.
// R14 = R11 champion (49.4us) + lockstep-breaking desync (no structural change).
// Model (R3..R13): MfmaUtil 27% + VALUBusy 30% + DS-pipe ~43% SUM to the
// duration — zero pipe overlap. R7 (counted vmcnt) identical-to-decimal =>
// drain was never the cost; the cost is all 8 waves/CU issuing ds_read bursts
// simultaneously between shared barriers, then MFMA bursts simultaneously.
// Desync edits (math/layout/grid/barriers untouched):
//  1. intra-wave SW pipeline: reg-double-buffered W frags; et+1 ds_reads issue
//     before et MFMAs+folds (DS and matrix interleave within each wave).
//  2. per-wave et rotation (e0 = wave&3): waves of a block touch different
//     chunk quarters at any instant (accumulation order change only).
//  3. block-parity chunk rotation (kk = parity*4+i mod 8): co-resident blocks
//     walk chunks 4-apart; one block computes while the other stages/reads.
//  + f32x2 packed folds (v_pk_fma candidates).
//  - launch_bounds(256,1): frag dbuf pushes VGPR ~160 > the 128 cap of (,2)
//    (R8 spill lesson). Occupancy stays LDS-capped at 2 blocks/CU = 8 waves.

typedef __attribute__((ext_vector_type(8))) __bf16 bf16x8;
typedef __attribute__((ext_vector_type(8))) unsigned short us8;
typedef __attribute__((ext_vector_type(4))) float f32x4;
typedef __attribute__((ext_vector_type(2))) float f32x2;

static __device__ __forceinline__ unsigned short f2bf(float f) {
  unsigned u = __float_as_uint(f);
  u += 0x7FFFu + ((u >> 16) & 1u);   // round-to-nearest-even
  return (unsigned short)(u >> 16);
}

static __device__ __forceinline__ bf16x8 as_bf(us8 u) {
  bf16x8 r;
  __builtin_memcpy(&r, &u, sizeof(r));
  return r;
}

// ---------------- prep (R11 elementwise, UNCHANGED layouts) ----------------
// wsW[t*8+j] = f2bf(W_side[k][d = s*32 + q*8 + j][e = (h*4+et')*16 + l15])
//   t: u=t&2047, cc=t>>11; lane=u&63, s=(u>>6)&3, et'=(u>>8)&3, side=(u>>10)&1;
//   h=cc&1, k=cc>>1; q=lane>>4, l15=lane&15.
// wsV[u*8+j] = f2bf(V[l15*256 + cs*32 + q*8 + j]), u: lane=u&63, cs=u>>6.
__global__ void ntn_prep(const float* __restrict__ W1, const float* __restrict__ W2,
                         const float* __restrict__ V,
                         unsigned short* __restrict__ wsW, unsigned short* __restrict__ wsV) {
  int e2 = blockIdx.x * 256 + threadIdx.x;
  if (e2 < 524288) {
    int j = e2 & 7, t = e2 >> 3;
    int u = t & 2047, cc = t >> 11;
    int lane = u & 63, s = (u >> 6) & 3, et2 = (u >> 8) & 3, side = (u >> 10) & 1;
    int h = cc & 1, k = cc >> 1;
    int q = lane >> 4, l15 = lane & 15;
    int et = h * 4 + et2;
    const float* W = side ? W2 : W1;
    wsW[e2] = f2bf(W[k * 16384 + (s * 32 + q * 8 + j) * 128 + (et * 16 + l15)]);
  } else if (e2 < 528384) {
    int v2 = e2 - 524288;
    int j = v2 & 7, u = v2 >> 3;
    int lane = u & 63, cs = u >> 6;
    int q = lane >> 4, l15 = lane & 15;
    wsV[v2] = f2bf(V[l15 * 256 + cs * 32 + q * 8 + j]);
  }
}

// ---------------- main ----------------
__global__ __launch_bounds__(256, 1) void ntn_main(
    const float* __restrict__ x1, const float* __restrict__ x2,
    const float* __restrict__ b,
    const unsigned short* __restrict__ wsW, const unsigned short* __restrict__ wsV,
    float* __restrict__ out) {
  __shared__ uint4 ldsW[2][2048];   // two 32KB chunk slots = 64KB

  const int tid = threadIdx.x;
  const int lane = tid & 63, wave = tid >> 6;
  const int q = lane >> 4, l15 = lane & 15;
  const int kh = blockIdx.x & 1;          // k range [8kh, 8kh+8)
  const int rb = blockIdx.x >> 1;         // 128-row group
  const int rowbase = rb * 128 + wave * 32;
  const int par = (blockIdx.x >> 1) & 1;  // co-resident-block desync parity

  const f32x4 zero4 = {0.f, 0.f, 0.f, 0.f};

  // async stage of one 32KB chunk into an LDS slot (8 glds x 64 lanes x 16B / wave)
  auto stage = [&](int cc, int slot) {
    const unsigned short* src = wsW + (size_t)cc * 16384 + (size_t)(wave * 512 + lane) * 8;
    uint4* dst = &ldsW[slot][wave * 512];
#pragma unroll
    for (int i = 0; i < 8; ++i)
      __builtin_amdgcn_global_load_lds(
          (__attribute__((address_space(1))) void*)(void*)(src + i * 512),
          (__attribute__((address_space(3))) void*)(dst + i * 64), 16, 0, 0);
  };

  const int kk0 = par * 4;                 // rotated chunk order start
  stage(kh * 16 + 2 * kk0, 0);             // first chunk (kk0, h=0)

  // ---- X fragments (B-operand), bf16, k-invariant, in registers (verbatim) ----
  bf16x8 xb[2][2][4];
#pragma unroll
  for (int side = 0; side < 2; ++side) {
    const float* xp0 = side ? x2 : x1;
#pragma unroll
    for (int nt = 0; nt < 2; ++nt) {
#pragma unroll
      for (int s = 0; s < 4; ++s) {
        const float* p = xp0 + (size_t)(rowbase + nt * 16 + l15) * 128 + s * 32 + q * 8;
        float4 v0 = *(const float4*)p;
        float4 v1 = *(const float4*)(p + 4);
        us8 uu;
        uu[0] = f2bf(v0.x); uu[1] = f2bf(v0.y); uu[2] = f2bf(v0.z); uu[3] = f2bf(v0.w);
        uu[4] = f2bf(v1.x); uu[5] = f2bf(v1.y); uu[6] = f2bf(v1.z); uu[7] = f2bf(v1.w);
        xb[side][nt][s] = as_bf(uu);
      }
    }
  }

  // ---- part2 + b via MFMA (A = V frags; B = X frags), in registers (verbatim) ----
  f32x4 accP[2];
  {
    bf16x8 vf[8];
#pragma unroll
    for (int cs = 0; cs < 8; ++cs)
      vf[cs] = as_bf(*(const us8*)(wsV + (size_t)(cs * 64 + lane) * 8));
    float4 bv = *(const float4*)(b + q * 4);
#pragma unroll
    for (int nt = 0; nt < 2; ++nt) {
      f32x4 a = zero4;
#pragma unroll
      for (int cs = 0; cs < 8; ++cs)
        a = __builtin_amdgcn_mfma_f32_16x16x32_bf16(vf[cs], xb[cs >> 2][nt][cs & 3], a, 0, 0, 0);
      a.x += bv.x; a.y += bv.y; a.z += bv.z; a.w += bv.w;
      accP[nt] = a;   // lane quad q holds part2+b for k = q*4 + reg
    }
  }

  // f32x2 packed fold accumulators
  f32x2 nmv[2], q1v[2], q2v[2];
#pragma unroll
  for (int nt = 0; nt < 2; ++nt) {
    nmv[nt] = (f32x2){0.f, 0.f}; q1v[nt] = (f32x2){0.f, 0.f}; q2v[nt] = (f32x2){0.f, 0.f};
  }

  // load one et's 8 W-fragments from an LDS slot into named register buffers
  auto ldfr = [&](int slot, int et, bf16x8 (&wa)[4], bf16x8 (&wb)[4]) {
#pragma unroll
    for (int s = 0; s < 4; ++s) {
      wa[s] = as_bf(*(const us8*)&ldsW[slot][et * 256 + s * 64 + lane]);
      wb[s] = as_bf(*(const us8*)&ldsW[slot][1024 + et * 256 + s * 64 + lane]);
    }
  };

  const int e0 = wave & 3;   // per-wave et rotation

  // compute one chunk: SW-pipelined (et+1 ds_reads issued before et MFMAs)
  auto compute = [&](int slot) {
    bf16x8 waA[4], wbA[4], waB[4], wbB[4];
    ldfr(slot, e0, waA, wbA);
#pragma unroll
    for (int ei = 0; ei < 4; ++ei) {
      bf16x8 (&wac)[4] = (ei & 1) ? waB : waA;
      bf16x8 (&wbc)[4] = (ei & 1) ? wbB : wbA;
      bf16x8 (&wan)[4] = (ei & 1) ? waA : waB;
      bf16x8 (&wbn)[4] = (ei & 1) ? wbA : wbB;
      if (ei < 3) ldfr(slot, (e0 + ei + 1) & 3, wan, wbn);
#pragma unroll
      for (int nt = 0; nt < 2; ++nt) {
        f32x4 a1 = zero4, a2 = zero4;
#pragma unroll
        for (int s = 0; s < 4; ++s)
          a1 = __builtin_amdgcn_mfma_f32_16x16x32_bf16(wac[s], xb[0][nt][s], a1, 0, 0, 0);
#pragma unroll
        for (int s = 0; s < 4; ++s)
          a2 = __builtin_amdgcn_mfma_f32_16x16x32_bf16(wbc[s], xb[1][nt][s], a2, 0, 0, 0);
        f32x2 a1lo = {a1.x, a1.y}, a1hi = {a1.z, a1.w};
        f32x2 a2lo = {a2.x, a2.y}, a2hi = {a2.z, a2.w};
        nmv[nt] += a1lo * a2lo; nmv[nt] += a1hi * a2hi;
        q1v[nt] += a1lo * a1lo; q1v[nt] += a1hi * a1hi;
        q2v[nt] += a2lo * a2lo; q2v[nt] += a2hi * a2hi;
      }
    }
  };

#pragma unroll 1
  for (int i = 0; i < 8; ++i) {
    const int kk = (kk0 + i) & 7;          // rotated chunk order
    const int cbase = kh * 16 + 2 * kk;
    __syncthreads();                       // chunk (kk, h=0) in slot0; slot1 free
    stage(cbase + 1, 1);
    compute(0);
    __syncthreads();                       // chunk (kk, h=1) in slot1; slot0 free
    if (i < 7) stage(kh * 16 + 2 * ((kk0 + i + 1) & 7), 0);
    compute(1);

    const int k = kh * 8 + kk;
    const int qo = k >> 2;                 // owning lane quad
    const int r  = k & 3;
#pragma unroll
    for (int nt = 0; nt < 2; ++nt) {
      float n = nmv[nt].x + nmv[nt].y;
      float s1 = q1v[nt].x + q1v[nt].y;
      float s2 = q2v[nt].x + q2v[nt].y;
      n  += __shfl_xor(n, 16);  n  += __shfl_xor(n, 32);
      s1 += __shfl_xor(s1, 16); s1 += __shfl_xor(s1, 32);
      s2 += __shfl_xor(s2, 16); s2 += __shfl_xor(s2, 32);
      float d1 = fmaxf(sqrtf(s1), 1e-8f);
      float d2 = fmaxf(sqrtf(s2), 1e-8f);
      float p1 = n / (d1 * d2);
      float pc = (r == 0) ? accP[nt].x : (r == 1) ? accP[nt].y
               : (r == 2) ? accP[nt].z : accP[nt].w;
      if (q == qo)
        out[(size_t)(rowbase + nt * 16 + l15) * 16 + k] = fmaxf(p1 + pc, 0.f);
      nmv[nt] = (f32x2){0.f, 0.f}; q1v[nt] = (f32x2){0.f, 0.f}; q2v[nt] = (f32x2){0.f, 0.f};
    }
  }
}

extern "C" void kernel_launch(void* const* d_in, const int* in_sizes, int n_in,
                              void* d_out, int out_size, void* d_ws, size_t ws_size,
                              hipStream_t stream) {
  const float* x1 = (const float*)d_in[0];
  const float* x2 = (const float*)d_in[1];
  const float* W1 = (const float*)d_in[2];
  const float* W2 = (const float*)d_in[3];
  const float* V  = (const float*)d_in[4];
  const float* b  = (const float*)d_in[5];
  float* out = (float*)d_out;
  unsigned short* wsW = (unsigned short*)d_ws;
  unsigned short* wsV = wsW + (size_t)65536 * 8;   // 1MB offset

  ntn_prep<<<2064, 256, 0, stream>>>(W1, W2, V, wsW, wsV);
  ntn_main<<<512, 256, 0, stream>>>(x1, x2, b, wsW, wsV, out);
}